// Round 11
// baseline (56.880 us; speedup 1.0000x reference)
//
#include <hip/hip_runtime.h>

#define WIN    7
#define IMH    640
#define IMW    640
#define OHH    634            // IMH - WIN + 1
#define OWW    634
#define NB     64
#define NBANDS 32
#define BROWS  20             // 31*20 + 14 = 634 output rows
#define NCT    5              // column tiles of 128 output cols
#define NTASK  (NB * NBANDS * NCT)   // 10240 wave-tasks
#define WPB    4              // waves per block (256 threads)
#define NBLK   (NTASK / WPB)  // 2560 blocks -> 2560 partials
#define DEPTH  4              // prefetch depth (rows in flight)
#define NSLOT  (DEPTH + 1)    // mod-5 buffer slots

// SSIM from RAW 7x7 window sums (Ss,Sd,Sss,Sdd), scale-cancelled by 49^2.
__device__ __forceinline__ float ssim_val(const float4& V, float C1s, float C2s) {
    const float covh = (49.0f / 48.0f) * 0.5f;
    const float a  = V.x * V.x, b = V.y * V.y;
    const float pd = a - b, ps = a + b;
    const float A1 = fmaf(0.5f, pd, C1s);
    const float B1 = fmaf(0.5f, ps, C1s);
    const float t1 = V.z - V.w, t2 = V.z + V.w;
    const float w1 = fmaf(49.0f, t1, -pd);
    const float w2 = fmaf(49.0f, t2, -ps);
    const float A2 = fmaf(covh, w1, C2s);
    const float B2 = fmaf(covh, w2, C2s);
    return (A1 * A2) * __builtin_amdgcn_rcpf(B1 * B2);
}

// Fully-unrolled band loop, DEPTH-4 register prefetch (mod-5 buffers).
// NROWS compile-time => buffer slot (u%5), ring slot (u%7), DOSSIM all
// static (rule #20). Rows u+1..u+4 in flight while row u computes (~800cy
// of compute between issue and wait) -> covers HBM-miss latency; each wave
// is the first toucher of its private 128-col strip, so most row-loads ARE
// HBM misses (r10 post-mortem).
template<int NROWS>
__device__ double band_loop(const float* __restrict__ Xp,
                            const float* __restrict__ Yp,
                            float C1s, float C2s, bool active)
{
    float4 ring0[WIN], ring1[WIN];
    #pragma unroll
    for (int u = 0; u < WIN; ++u) {
        ring0[u] = make_float4(0.f, 0.f, 0.f, 0.f);
        ring1[u] = make_float4(0.f, 0.f, 0.f, 0.f);
    }
    float4 V0 = make_float4(0.f, 0.f, 0.f, 0.f);
    float4 V1 = make_float4(0.f, 0.f, 0.f, 0.f);

    float4 bufx[NSLOT][2], bufy[NSLOT][2];   // mod-5 slots (all static idx)
    double acc  = 0.0;
    float  esum = 0.f;

#define LOADROW(P, R) do {                                                    \
    const size_t o_ = (size_t)(R) * IMW;                                      \
    bufx[P][0] = *(const float4*)(Xp + o_);                                   \
    bufx[P][1] = *(const float4*)(Xp + o_ + 4);                               \
    bufy[P][0] = *(const float4*)(Yp + o_);                                   \
    bufy[P][1] = *(const float4*)(Yp + o_ + 4);                               \
} while (0)

    // prologue: rows 0..3 in flight
    LOADROW(0, 0); LOADROW(1, 1); LOADROW(2, 2); LOADROW(3, 3);

    #pragma unroll
    for (int u = 0; u < NROWS; ++u) {
        if (u + DEPTH < NROWS) LOADROW((u + DEPTH) % NSLOT, u + DEPTH);

        {
            const float4 xa = bufx[u % NSLOT][0], xb = bufx[u % NSLOT][1];
            const float4 ya = bufy[u % NSLOT][0], yb = bufy[u % NSLOT][1];

            const float4 sa = make_float4(xa.x + ya.x, xa.y + ya.y,
                                          xa.z + ya.z, xa.w + ya.w);
            const float4 sb = make_float4(xb.x + yb.x, xb.y + yb.y,
                                          xb.z + yb.z, xb.w + yb.w);
            const float4 da = make_float4(xa.x - ya.x, xa.y - ya.y,
                                          xa.z - ya.z, xa.w - ya.w);
            const float4 db = make_float4(xb.x - yb.x, xb.y - yb.y,
                                          xb.z - yb.z, xb.w - yb.w);

            const float hs0 = ((sa.x + sa.y) + (sa.z + sa.w))
                            + ((sb.x + sb.y) + sb.z);
            const float hs1 = (hs0 - sa.x) + sb.w;
            const float hd0 = ((da.x + da.y) + (da.z + da.w))
                            + ((db.x + db.y) + db.z);
            const float hd1 = (hd0 - da.x) + db.w;
            const float hss0 = fmaf(sa.x, sa.x, fmaf(sa.y, sa.y,
                               fmaf(sa.z, sa.z, fmaf(sa.w, sa.w,
                               fmaf(sb.x, sb.x, fmaf(sb.y, sb.y,
                                    sb.z * sb.z))))));
            const float hss1 = fmaf(sb.w, sb.w, hss0 - sa.x * sa.x);
            const float hdd0 = fmaf(da.x, da.x, fmaf(da.y, da.y,
                               fmaf(da.z, da.z, fmaf(da.w, da.w,
                               fmaf(db.x, db.x, fmaf(db.y, db.y,
                                    db.z * db.z))))));
            const float hdd1 = fmaf(db.w, db.w, hdd0 - da.x * da.x);

            const int s = u % WIN;      // compile-time (loop fully unrolled)
            V0.x += hs0  - ring0[s].x;  V0.y += hd0  - ring0[s].y;
            V0.z += hss0 - ring0[s].z;  V0.w += hdd0 - ring0[s].w;
            V1.x += hs1  - ring1[s].x;  V1.y += hd1  - ring1[s].y;
            V1.z += hss1 - ring1[s].z;  V1.w += hdd1 - ring1[s].w;
            ring0[s] = make_float4(hs0, hd0, hss0, hdd0);
            ring1[s] = make_float4(hs1, hd1, hss1, hdd1);

            if (u >= WIN - 1 && active) {
                const float e0 = ssim_val(V0, C1s, C2s);
                const float e1 = ssim_val(V1, C1s, C2s);
                esum += e0 + e1;
            }
        }

        if (u % WIN == WIN - 1 || u == NROWS - 1) {   // compile-time
            acc += (double)esum;
            esum = 0.f;
        }
    }
#undef LOADROW
    return acc;
}

// 4 independent waves per block; only interaction is the final LDS reduce.
// launch_bounds(.,1): NO VGPR cap -> allocator floats instead of spilling
// (r5 lesson: forced cap + high demand = scratch traffic).
__global__ __launch_bounds__(256, 1) void ssim_stream(
    const float* __restrict__ X, const float* __restrict__ Y,
    const float* __restrict__ dr, double* __restrict__ partial)
{
    __shared__ double sred[WPB];

    const int tid  = threadIdx.x;
    const int lane = tid & 63;
    const int wv   = tid >> 6;

    const int task = blockIdx.x * WPB + wv;   // 0..10239
    const int tile = task % NCT;              // 4 block-waves = adjacent tiles
    const int band = (task / NCT) % NBANDS;
    const int b    = task / (NCT * NBANDS);

    const int r0 = band * BROWS;

    const int  ocol   = tile * 128 + 2 * lane;
    const int  cbase  = min(ocol, IMW - 8);
    const bool active = (ocol <= OWW - 2);

    const size_t ioff = (size_t)b * IMH * IMW + (size_t)r0 * IMW + cbase;
    const float* Xp = X + ioff;
    const float* Yp = Y + ioff;

    const float drv = dr[b];
    const float C1s = 2401.0f * (0.01f * drv) * (0.01f * drv);
    const float C2s = 2401.0f * (0.03f * drv) * (0.03f * drv);

    double acc;
    if (band < NBANDS - 1) {
        acc = band_loop<BROWS + WIN - 1>(Xp, Yp, C1s, C2s, active);   // 26 rows
    } else {
        acc = band_loop<IMH - (NBANDS - 1) * BROWS>(Xp, Yp, C1s, C2s, active); // 20
    }

    for (int off = 32; off > 0; off >>= 1)
        acc += __shfl_down(acc, off, 64);
    if (lane == 0) sred[wv] = acc;
    __syncthreads();
    if (tid == 0) {
        double t = 0.0;
        #pragma unroll
        for (int k = 0; k < WPB; ++k) t += sred[k];
        partial[blockIdx.x] = t;
    }
}

__global__ __launch_bounds__(512) void ssim_reduce(
    const double* __restrict__ partial, int n2, float* __restrict__ out)
{
    const double2* p2 = (const double2*)partial;
    double acc = 0.0;
    for (int i = threadIdx.x; i < n2; i += 512) {
        double2 v = p2[i];
        acc += v.x + v.y;
    }
    for (int off = 32; off > 0; off >>= 1)
        acc += __shfl_down(acc, off, 64);
    __shared__ double sred[8];
    if ((threadIdx.x & 63) == 0) sred[threadIdx.x >> 6] = acc;
    __syncthreads();
    if (threadIdx.x == 0) {
        double t = 0.0;
        #pragma unroll
        for (int k = 0; k < 8; ++k) t += sred[k];
        double denom = (double)NB * (double)OHH * (double)OWW;
        out[0] = (float)(t / denom);
    }
}

extern "C" void kernel_launch(void* const* d_in, const int* in_sizes, int n_in,
                              void* d_out, int out_size, void* d_ws, size_t ws_size,
                              hipStream_t stream) {
    const float* X  = (const float*)d_in[0];
    const float* Y  = (const float*)d_in[1];
    const float* dr = (const float*)d_in[2];
    // d_in[3] is w = ones/49; constant-folded in-kernel.
    double* partial = (double*)d_ws;   // 2560 * 8 B = 20 KB scratch

    ssim_stream<<<NBLK, 256, 0, stream>>>(X, Y, dr, partial);
    ssim_reduce<<<1, 512, 0, stream>>>(partial, NBLK / 2, (float*)d_out);
}

// Round 12
// 54.365 us; speedup vs baseline: 1.0463x; 1.0463x over previous
//
#include <hip/hip_runtime.h>

#define WIN    7
#define IMH    640
#define IMW    640
#define OHH    634            // IMH - WIN + 1
#define OWW    634
#define NB     64
#define NBANDS 32
#define BROWS  20             // 31*20 + 14 = 634 output rows
#define NCT    5              // column tiles of 128 output cols
#define NTASK  (NB * NBANDS * NCT)   // 10240 wave-tasks
#define WPB    4              // waves per block (256 threads)
#define NBLK   (NTASK / WPB)  // 2560 blocks -> 2560 partials
#define DEPTH  2              // prefetch depth (r10 sweet spot; r11 depth-4 regressed)
#define NSLOT  (DEPTH + 1)

// float2 helpers: (s,d) packed in .x/.y — every op is component-wise so the
// SLP vectorizer can form v_pk_add_f32 / v_pk_fma_f32 (VOP3P, 2x fp32/instr).
__device__ __forceinline__ float2 f2add(float2 a, float2 b) {
    return make_float2(a.x + b.x, a.y + b.y);
}
__device__ __forceinline__ float2 f2sub(float2 a, float2 b) {
    return make_float2(a.x - b.x, a.y - b.y);
}
__device__ __forceinline__ float2 f2fma(float2 a, float2 b, float2 c) {
    return make_float2(fmaf(a.x, b.x, c.x), fmaf(a.y, b.y, c.y));
}

// SSIM from RAW 7x7 window sums Vsd=(Ss,Sd), Vq=(Sss,Sdd), scale-cancelled
// by 49^2 (C1s/C2s pre-multiplied by 2401).
__device__ __forceinline__ float ssim_val(float2 Vsd, float2 Vq,
                                          float C1s, float C2s) {
    const float covh = (49.0f / 48.0f) * 0.5f;
    const float a  = Vsd.x * Vsd.x, b = Vsd.y * Vsd.y;
    const float pd = a - b, ps = a + b;
    const float A1 = fmaf(0.5f, pd, C1s);
    const float B1 = fmaf(0.5f, ps, C1s);
    const float t1 = Vq.x - Vq.y, t2 = Vq.x + Vq.y;
    const float w1 = fmaf(49.0f, t1, -pd);
    const float w2 = fmaf(49.0f, t2, -ps);
    const float A2 = fmaf(covh, w1, C2s);
    const float B2 = fmaf(covh, w2, C2s);
    return (A1 * A2) * __builtin_amdgcn_rcpf(B1 * B2);
}

// Fully-unrolled band loop, DEPTH-2 register prefetch (mod-3 buffers, r10's
// proven schedule). All indices static (rule #20). Row body rewritten in
// packed (s,d) float2 form.
template<int NROWS>
__device__ double band_loop(const float* __restrict__ Xp,
                            const float* __restrict__ Yp,
                            float C1s, float C2s, bool active)
{
    // rings: A = (hs,hd) 7-tap sums, B = (hss,hdd) square sums, per col.
    float2 rA0[WIN], rB0[WIN], rA1[WIN], rB1[WIN];
    #pragma unroll
    for (int u = 0; u < WIN; ++u) {
        rA0[u] = make_float2(0.f, 0.f); rB0[u] = make_float2(0.f, 0.f);
        rA1[u] = make_float2(0.f, 0.f); rB1[u] = make_float2(0.f, 0.f);
    }
    float2 VA0 = make_float2(0.f, 0.f), VB0 = make_float2(0.f, 0.f);
    float2 VA1 = make_float2(0.f, 0.f), VB1 = make_float2(0.f, 0.f);

    float4 bufx[NSLOT][2], bufy[NSLOT][2];   // mod-3 slots (all static idx)
    double acc  = 0.0;
    float  esum = 0.f;

#define LOADROW(P, R) do {                                                    \
    const size_t o_ = (size_t)(R) * IMW;                                      \
    bufx[P][0] = *(const float4*)(Xp + o_);                                   \
    bufx[P][1] = *(const float4*)(Xp + o_ + 4);                               \
    bufy[P][0] = *(const float4*)(Yp + o_);                                   \
    bufy[P][1] = *(const float4*)(Yp + o_ + 4);                               \
} while (0)

    LOADROW(0, 0); LOADROW(1, 1);       // prologue: rows 0,1 in flight

    #pragma unroll
    for (int u = 0; u < NROWS; ++u) {
        if (u + DEPTH < NROWS) LOADROW((u + DEPTH) % NSLOT, u + DEPTH);

        {
            const float4 xa = bufx[u % NSLOT][0], xb = bufx[u % NSLOT][1];
            const float4 ya = bufy[u % NSLOT][0], yb = bufy[u % NSLOT][1];

            // packed (s,d) per column k: sd[k] = (x+y, x-y)
            float2 sd[8];
            sd[0] = make_float2(xa.x + ya.x, xa.x - ya.x);
            sd[1] = make_float2(xa.y + ya.y, xa.y - ya.y);
            sd[2] = make_float2(xa.z + ya.z, xa.z - ya.z);
            sd[3] = make_float2(xa.w + ya.w, xa.w - ya.w);
            sd[4] = make_float2(xb.x + yb.x, xb.x - yb.x);
            sd[5] = make_float2(xb.y + yb.y, xb.y - yb.y);
            sd[6] = make_float2(xb.z + yb.z, xb.z - yb.z);
            sd[7] = make_float2(xb.w + yb.w, xb.w - yb.w);

            // horizontal 7-tap sums (packed): hA = (hs,hd)
            const float2 m01 = f2add(sd[0], sd[1]);
            const float2 m23 = f2add(sd[2], sd[3]);
            const float2 m45 = f2add(sd[4], sd[5]);
            const float2 hA0 = f2add(f2add(m01, m23), f2add(m45, sd[6]));
            const float2 hA1 = f2add(f2sub(hA0, sd[0]), sd[7]);

            // horizontal 7-tap square sums (packed): hB = (hss,hdd)
            float2 q = f2fma(sd[1], sd[1], f2fma(sd[0], sd[0],
                       make_float2(0.f, 0.f)));
            q = f2fma(sd[3], sd[3], f2fma(sd[2], sd[2], q));
            q = f2fma(sd[5], sd[5], f2fma(sd[4], sd[4], q));
            const float2 hB0 = f2fma(sd[6], sd[6], q);
            const float2 hB1 = f2fma(sd[7], sd[7],
                               f2fma(make_float2(-sd[0].x, -sd[0].y), sd[0], hB0));

            // running vertical sums: V += h_new - ring[row-7] (slot static)
            const int s = u % WIN;
            VA0 = f2add(VA0, f2sub(hA0, rA0[s]));
            VB0 = f2add(VB0, f2sub(hB0, rB0[s]));
            VA1 = f2add(VA1, f2sub(hA1, rA1[s]));
            VB1 = f2add(VB1, f2sub(hB1, rB1[s]));
            rA0[s] = hA0; rB0[s] = hB0;
            rA1[s] = hA1; rB1[s] = hB1;

            if (u >= WIN - 1 && active) {
                const float e0 = ssim_val(VA0, VB0, C1s, C2s);
                const float e1 = ssim_val(VA1, VB1, C1s, C2s);
                esum += e0 + e1;
            }
        }

        if (u % WIN == WIN - 1 || u == NROWS - 1) {   // compile-time
            acc += (double)esum;
            esum = 0.f;
        }
    }
#undef LOADROW
    return acc;
}

// 4 independent waves per block; only interaction is the final LDS reduce.
__global__ __launch_bounds__(256, 2) void ssim_stream(
    const float* __restrict__ X, const float* __restrict__ Y,
    const float* __restrict__ dr, double* __restrict__ partial)
{
    __shared__ double sred[WPB];

    const int tid  = threadIdx.x;
    const int lane = tid & 63;
    const int wv   = tid >> 6;

    const int task = blockIdx.x * WPB + wv;   // 0..10239
    const int tile = task % NCT;              // 4 block-waves = adjacent tiles
    const int band = (task / NCT) % NBANDS;
    const int b    = task / (NCT * NBANDS);

    const int r0 = band * BROWS;

    const int  ocol   = tile * 128 + 2 * lane;
    const int  cbase  = min(ocol, IMW - 8);
    const bool active = (ocol <= OWW - 2);

    const size_t ioff = (size_t)b * IMH * IMW + (size_t)r0 * IMW + cbase;
    const float* Xp = X + ioff;
    const float* Yp = Y + ioff;

    const float drv = dr[b];
    const float C1s = 2401.0f * (0.01f * drv) * (0.01f * drv);
    const float C2s = 2401.0f * (0.03f * drv) * (0.03f * drv);

    double acc;
    if (band < NBANDS - 1) {
        acc = band_loop<BROWS + WIN - 1>(Xp, Yp, C1s, C2s, active);   // 26 rows
    } else {
        acc = band_loop<IMH - (NBANDS - 1) * BROWS>(Xp, Yp, C1s, C2s, active); // 20
    }

    for (int off = 32; off > 0; off >>= 1)
        acc += __shfl_down(acc, off, 64);
    if (lane == 0) sred[wv] = acc;
    __syncthreads();
    if (tid == 0) {
        double t = 0.0;
        #pragma unroll
        for (int k = 0; k < WPB; ++k) t += sred[k];
        partial[blockIdx.x] = t;
    }
}

__global__ __launch_bounds__(512) void ssim_reduce(
    const double* __restrict__ partial, int n2, float* __restrict__ out)
{
    const double2* p2 = (const double2*)partial;
    double acc = 0.0;
    for (int i = threadIdx.x; i < n2; i += 512) {
        double2 v = p2[i];
        acc += v.x + v.y;
    }
    for (int off = 32; off > 0; off >>= 1)
        acc += __shfl_down(acc, off, 64);
    __shared__ double sred[8];
    if ((threadIdx.x & 63) == 0) sred[threadIdx.x >> 6] = acc;
    __syncthreads();
    if (threadIdx.x == 0) {
        double t = 0.0;
        #pragma unroll
        for (int k = 0; k < 8; ++k) t += sred[k];
        double denom = (double)NB * (double)OHH * (double)OWW;
        out[0] = (float)(t / denom);
    }
}

extern "C" void kernel_launch(void* const* d_in, const int* in_sizes, int n_in,
                              void* d_out, int out_size, void* d_ws, size_t ws_size,
                              hipStream_t stream) {
    const float* X  = (const float*)d_in[0];
    const float* Y  = (const float*)d_in[1];
    const float* dr = (const float*)d_in[2];
    // d_in[3] is w = ones/49; constant-folded in-kernel.
    double* partial = (double*)d_ws;   // 2560 * 8 B = 20 KB scratch

    ssim_stream<<<NBLK, 256, 0, stream>>>(X, Y, dr, partial);
    ssim_reduce<<<1, 512, 0, stream>>>(partial, NBLK / 2, (float*)d_out);
}

// Round 13
// 48.375 us; speedup vs baseline: 1.1758x; 1.1238x over previous
//
#include <hip/hip_runtime.h>

#define WIN    7
#define IMH    640
#define IMW    640
#define OHH    634            // IMH - WIN + 1
#define OWW    634
#define NB     64
#define NBANDS 32
#define BROWS  20             // 31*20 + 14 = 634 output rows
#define NCT    5              // column tiles of 128 output cols
#define NTASK  (NB * NBANDS * NCT)   // 10240 wave-tasks
#define WPB    4              // waves per block (256 threads)
#define NBLK   (NTASK / WPB)  // 2560 blocks -> 2560 partials
#define DEPTH  2              // prefetch depth (r10 sweet spot)
#define NSLOT  (DEPTH + 1)

// Native 2-wide float vector: clang keeps <2 x float> ops in IR and ISel
// emits v_pk_add_f32 / v_pk_mul_f32 / v_pk_fma_f32 (VOP3P, full rate on
// CDNA -> 2 fp32 ops per instruction). r12's make_float2 helpers scalarized
// and never re-vectorized — this is the fix.
typedef float v2f __attribute__((ext_vector_type(2)));

struct __align__(16) f4v { v2f lo, hi; };   // loads as global_load_dwordx4

// Fully-unrolled band loop, DEPTH-2 register prefetch (mod-3 buffers, r10's
// proven schedule). All indices static (rule #20). Row body in packed
// column-pair (v2f) form; SSIM epilogue packed across the 2 output cols with
// one combined rcp: e0+e1 = (N0*D1 + N1*D0) * rcp(D0*D1).
template<int NROWS>
__device__ double band_loop(const float* __restrict__ Xp,
                            const float* __restrict__ Yp,
                            float C1s, float C2s, bool active)
{
    const v2f C1v  = {C1s, C1s};
    const v2f C2v  = {C2s, C2s};
    const v2f covh = {(49.0f / 48.0f) * 0.5f, (49.0f / 48.0f) * 0.5f};
    const v2f zero = {0.f, 0.f};

    // rings of horizontal 7-tap sums, packed (col0,col1) per moment
    v2f rS[WIN], rD[WIN], rSS[WIN], rDD[WIN];
    #pragma unroll
    for (int u = 0; u < WIN; ++u) { rS[u]=zero; rD[u]=zero; rSS[u]=zero; rDD[u]=zero; }
    v2f VS = zero, VD = zero, VSS = zero, VDD = zero;

    f4v bufx[NSLOT][2], bufy[NSLOT][2];   // mod-3 slots (all static idx)
    double acc  = 0.0;
    float  esum = 0.f;

#define LOADROW(P, R) do {                                                    \
    const size_t o_ = (size_t)(R) * IMW;                                      \
    bufx[P][0] = *(const f4v*)(Xp + o_);                                      \
    bufx[P][1] = *(const f4v*)(Xp + o_ + 4);                                  \
    bufy[P][0] = *(const f4v*)(Yp + o_);                                      \
    bufy[P][1] = *(const f4v*)(Yp + o_ + 4);                                  \
} while (0)

    LOADROW(0, 0); LOADROW(1, 1);       // prologue: rows 0,1 in flight

    #pragma unroll
    for (int u = 0; u < NROWS; ++u) {
        if (u + DEPTH < NROWS) LOADROW((u + DEPTH) % NSLOT, u + DEPTH);

        {
            const f4v xa = bufx[u % NSLOT][0], xb = bufx[u % NSLOT][1];
            const f4v ya = bufy[u % NSLOT][0], yb = bufy[u % NSLOT][1];

            // packed (s,d) per column pair: 8 pk adds
            const v2f s01 = xa.lo + ya.lo, s23 = xa.hi + ya.hi;
            const v2f s45 = xb.lo + yb.lo, s67 = xb.hi + yb.hi;
            const v2f d01 = xa.lo - ya.lo, d23 = xa.hi - ya.hi;
            const v2f d45 = xb.lo - yb.lo, d67 = xb.hi - yb.hi;

            // even/odd half-sum trees (pk): t.x = sum of even cols, t.y = odd
            const v2f ts  = (s01 + s23) + (s45 + s67);
            const v2f td  = (d01 + d23) + (d45 + d67);
            const v2f tqs = (s01*s01 + s23*s23) + (s45*s45 + s67*s67); // pk fma
            const v2f tqd = (d01*d01 + d23*d23) + (d45*d45 + d67*d67);

            // scalar tails: EO = sum over all 8 cols; h0 = EO - col7, h1 = EO - col0
            const float EOs  = ts.x + ts.y,   EOd  = td.x + td.y;
            const float EOss = tqs.x + tqs.y, EOdd = tqd.x + tqd.y;
            v2f hS, hD, hSS, hDD;
            hS.x  = EOs  - s67.y;           hS.y  = EOs  - s01.x;
            hD.x  = EOd  - d67.y;           hD.y  = EOd  - d01.x;
            hSS.x = EOss - s67.y * s67.y;   hSS.y = EOss - s01.x * s01.x;
            hDD.x = EOdd - d67.y * d67.y;   hDD.y = EOdd - d01.x * d01.x;

            // running vertical sums (pk): V += h_new - ring[row-7]
            const int sl = u % WIN;         // compile-time (fully unrolled)
            VS  += hS  - rS[sl];   VD  += hD  - rD[sl];
            VSS += hSS - rSS[sl];  VDD += hDD - rDD[sl];
            rS[sl] = hS; rD[sl] = hD; rSS[sl] = hSS; rDD[sl] = hDD;

            if (u >= WIN - 1 && active) {
                // SSIM packed across the two output cols (scale-cancelled by 49^2)
                const v2f a  = VS * VS, b = VD * VD;
                const v2f pd = a - b,  ps = a + b;
                const v2f A1 = 0.5f * pd + C1v;
                const v2f B1 = 0.5f * ps + C1v;
                const v2f t1 = VSS - VDD,  t2 = VSS + VDD;
                const v2f w1 = 49.0f * t1 - pd;
                const v2f w2 = 49.0f * t2 - ps;
                const v2f A2 = covh * w1 + C2v;
                const v2f B2 = covh * w2 + C2v;
                const v2f N  = A1 * A2, D = B1 * B2;
                // combined: e0+e1 = (N0*D1 + N1*D0) / (D0*D1)  (one rcp)
                const float Dp  = D.x * D.y;
                const float num = fmaf(N.y, D.x, N.x * D.y);
                esum = fmaf(num, __builtin_amdgcn_rcpf(Dp), esum);
            }
        }

        if (u % WIN == WIN - 1 || u == NROWS - 1) {   // compile-time
            acc += (double)esum;
            esum = 0.f;
        }
    }
#undef LOADROW
    return acc;
}

// 4 independent waves per block; only interaction is the final LDS reduce.
__global__ __launch_bounds__(256, 2) void ssim_stream(
    const float* __restrict__ X, const float* __restrict__ Y,
    const float* __restrict__ dr, double* __restrict__ partial)
{
    __shared__ double sred[WPB];

    const int tid  = threadIdx.x;
    const int lane = tid & 63;
    const int wv   = tid >> 6;

    const int task = blockIdx.x * WPB + wv;   // 0..10239
    const int tile = task % NCT;              // 4 block-waves = adjacent tiles
    const int band = (task / NCT) % NBANDS;
    const int b    = task / (NCT * NBANDS);

    const int r0 = band * BROWS;

    const int  ocol   = tile * 128 + 2 * lane;
    const int  cbase  = min(ocol, IMW - 8);
    const bool active = (ocol <= OWW - 2);

    const size_t ioff = (size_t)b * IMH * IMW + (size_t)r0 * IMW + cbase;
    const float* Xp = X + ioff;
    const float* Yp = Y + ioff;

    const float drv = dr[b];
    const float C1s = 2401.0f * (0.01f * drv) * (0.01f * drv);
    const float C2s = 2401.0f * (0.03f * drv) * (0.03f * drv);

    double acc;
    if (band < NBANDS - 1) {
        acc = band_loop<BROWS + WIN - 1>(Xp, Yp, C1s, C2s, active);   // 26 rows
    } else {
        acc = band_loop<IMH - (NBANDS - 1) * BROWS>(Xp, Yp, C1s, C2s, active); // 20
    }

    for (int off = 32; off > 0; off >>= 1)
        acc += __shfl_down(acc, off, 64);
    if (lane == 0) sred[wv] = acc;
    __syncthreads();
    if (tid == 0) {
        double t = 0.0;
        #pragma unroll
        for (int k = 0; k < WPB; ++k) t += sred[k];
        partial[blockIdx.x] = t;
    }
}

__global__ __launch_bounds__(512) void ssim_reduce(
    const double* __restrict__ partial, int n2, float* __restrict__ out)
{
    const double2* p2 = (const double2*)partial;
    double acc = 0.0;
    for (int i = threadIdx.x; i < n2; i += 512) {
        double2 v = p2[i];
        acc += v.x + v.y;
    }
    for (int off = 32; off > 0; off >>= 1)
        acc += __shfl_down(acc, off, 64);
    __shared__ double sred[8];
    if ((threadIdx.x & 63) == 0) sred[threadIdx.x >> 6] = acc;
    __syncthreads();
    if (threadIdx.x == 0) {
        double t = 0.0;
        #pragma unroll
        for (int k = 0; k < 8; ++k) t += sred[k];
        double denom = (double)NB * (double)OHH * (double)OWW;
        out[0] = (float)(t / denom);
    }
}

extern "C" void kernel_launch(void* const* d_in, const int* in_sizes, int n_in,
                              void* d_out, int out_size, void* d_ws, size_t ws_size,
                              hipStream_t stream) {
    const float* X  = (const float*)d_in[0];
    const float* Y  = (const float*)d_in[1];
    const float* dr = (const float*)d_in[2];
    // d_in[3] is w = ones/49; constant-folded in-kernel.
    double* partial = (double*)d_ws;   // 2560 * 8 B = 20 KB scratch

    ssim_stream<<<NBLK, 256, 0, stream>>>(X, Y, dr, partial);
    ssim_reduce<<<1, 512, 0, stream>>>(partial, NBLK / 2, (float*)d_out);
}